// Round 6
// baseline (268.951 us; speedup 1.0000x reference)
//
#include <hip/hip_runtime.h>
#include <math.h>

// ---------------------------------------------------------------------------
// JAX Threefry-2x32 (constexpr for key derivation, device for per-elem hash).
// ---------------------------------------------------------------------------
struct K2 { unsigned a, b; };

__host__ __device__ constexpr unsigned rotl32c(unsigned x, int r) {
  return (x << r) | (x >> (32 - r));
}

__host__ __device__ constexpr K2 threefry2x32(unsigned k0, unsigned k1,
                                              unsigned x0, unsigned x1) {
  const unsigned ks2 = k0 ^ k1 ^ 0x1BD11BDAu;
  const unsigned ks[3] = {k0, k1, ks2};
  const int rotA[4] = {13, 15, 26, 6};
  const int rotB[4] = {17, 29, 16, 24};
  x0 += k0; x1 += k1;
  for (int g = 0; g < 5; ++g) {
    const int* rr = (g & 1) ? rotB : rotA;
    for (int i = 0; i < 4; ++i) {
      x0 += x1;
      x1 = rotl32c(x1, rr[i]);
      x1 ^= x0;
    }
    x0 += ks[(g + 1) % 3];
    x1 += ks[(g + 2) % 3] + (unsigned)(g + 1);
  }
  return K2{x0, x1};
}

__host__ __device__ constexpr K2 hop_key(unsigned k) {
  K2 f = threefry2x32(0u, 42u, 0u, k);
  return threefry2x32(f.a, f.b, 0u, 1u);
}

constexpr K2 HK0 = hop_key(0u);
constexpr K2 HK1 = hop_key(1u);

// ---------------------------------------------------------------------------
// Kernel 1: hop-1 sampling. s1[i] = adj[node_ids[i/10]*128 + rand_col(i)].
// Tiny (10240 threads) but precomputing s1 de-serializes the hop-2 waves'
// dependency chains (s1 is L2-warm for kernel 2).
// ---------------------------------------------------------------------------
__global__ __launch_bounds__(256) void sample_hop1(
    const int* __restrict__ ids, const int* __restrict__ adj,
    int* __restrict__ out, int n) {
  int i = blockIdx.x * 256 + threadIdx.x;
  if (i >= n) return;
  K2 r = threefry2x32(HK0.a, HK0.b, 0u, (unsigned)i);
  int col = (int)((r.a ^ r.b) & 127u);
  out[i] = adj[(long long)ids[i / 10] * 128 + col];
}

// ---------------------------------------------------------------------------
// Kernel 2: gather-means (reads precomputed s1).
//   blocks 0..2559   : hop-2 sample (lanes 0..24) + 25-row mean -> nm1[m]
//   blocks 2560..2815: hop-1 10-row mean of F[s1] -> nm0[m0]
// One wave per output row; float4 per lane; 5-deep load batches.
// ---------------------------------------------------------------------------
__global__ __launch_bounds__(256) void sample_means(
    const int* __restrict__ s1, const int* __restrict__ adj,
    const float* __restrict__ feat, float* __restrict__ nm1,
    float* __restrict__ nm0) {
  const int blk = blockIdx.x;
  const int w = threadIdx.x >> 6;
  const int lane = threadIdx.x & 63;

  if (blk < 2560) {
    const int m = blk * 4 + w;  // 0..10239
    const int nid = s1[m];      // wave-uniform, L2-warm
    // hop-2 samples in lanes 0..24
    int srow;
    {
      unsigned i = (unsigned)(m * 25 + (lane < 25 ? lane : 0));
      K2 r = threefry2x32(HK1.a, HK1.b, 0u, i);
      srow = adj[(long long)nid * 128 + (int)((r.a ^ r.b) & 127u)];
    }
    float4 acc = make_float4(0.f, 0.f, 0.f, 0.f);
#pragma unroll
    for (int c = 0; c < 25; c += 5) {
      float4 v[5];
#pragma unroll
      for (int j = 0; j < 5; ++j) {
        long long row = (long long)__shfl(srow, c + j, 64);
        v[j] = *(const float4*)(feat + row * 256 + (lane << 2));
      }
#pragma unroll
      for (int j = 0; j < 5; ++j) {
        acc.x += v[j].x; acc.y += v[j].y; acc.z += v[j].z; acc.w += v[j].w;
      }
    }
    const float s = 1.f / 25.f;
    acc.x *= s; acc.y *= s; acc.z *= s; acc.w *= s;
    *(float4*)(nm1 + (long long)m * 256 + (lane << 2)) = acc;
  } else {
    const int m0 = (blk - 2560) * 4 + w;  // 0..1023
    const int srow = s1[(long long)m0 * 10 + (lane < 10 ? lane : 0)];
    float4 acc = make_float4(0.f, 0.f, 0.f, 0.f);
#pragma unroll
    for (int c = 0; c < 10; c += 5) {
      float4 v[5];
#pragma unroll
      for (int j = 0; j < 5; ++j) {
        long long row = (long long)__shfl(srow, c + j, 64);
        v[j] = *(const float4*)(feat + row * 256 + (lane << 2));
      }
#pragma unroll
      for (int j = 0; j < 5; ++j) {
        acc.x += v[j].x; acc.y += v[j].y; acc.z += v[j].z; acc.w += v[j].w;
      }
    }
    acc.x *= 0.1f; acc.y *= 0.1f; acc.z *= 0.1f; acc.w *= 0.1f;
    *(float4*)(nm0 + (long long)m0 * 256 + (lane << 2)) = acc;
  }
}

// ---------------------------------------------------------------------------
// Kernel 3: layer-0 GEMMs (4 configs, one dispatch, flat 1D decode).
// 64x64 tile, 4x4 micro, BK=16, float4 LDS fragments + register
// double-buffer prefetch of the next K-slab (hides global latency).
// C[m, ccol0 + nt*64 + n] = relu(A[row(m)] @ B[:, nt*64+n])
// ---------------------------------------------------------------------------
struct GemmCfg {
  const float* A; const int* idx; const float* B; float* C;
  int ccol0; int mtiles; int tiles;
};
struct GemmCfg4 { GemmCfg c[4]; };

__global__ __launch_bounds__(256) void gemm_relu_multi(GemmCfg4 cfgs) {
  int b = blockIdx.x, z = 0;
  while (z < 3 && b >= cfgs.c[z].tiles) { b -= cfgs.c[z].tiles; ++z; }
  const GemmCfg cfg = cfgs.c[z];
  const int mt = b % cfg.mtiles;
  const int nt = b / cfg.mtiles;

  __shared__ __align__(16) float As[16][68];  // transposed A tile, padded
  __shared__ __align__(16) float Bs[16][68];

  const int t = threadIdx.x;
  const int tx = t & 15, ty = t >> 4;

  const int arow = t >> 2;
  const int ak4 = (t & 3) << 2;
  const int grow = mt * 64 + arow;
  const long long asrc = cfg.idx ? (long long)cfg.idx[grow] : (long long)grow;
  const float* Ap = cfg.A + asrc * 256 + ak4;

  const int bkk = t >> 4;
  const int bn4 = (t & 15) << 2;
  const float* Bp = cfg.B + bkk * 128 + nt * 64 + bn4;

  float4 av = *(const float4*)Ap;
  float4 bv = *(const float4*)Bp;
  float acc[4][4] = {};

  for (int k0 = 0; k0 < 256; k0 += 16) {
    __syncthreads();
    As[ak4 + 0][arow] = av.x;
    As[ak4 + 1][arow] = av.y;
    As[ak4 + 2][arow] = av.z;
    As[ak4 + 3][arow] = av.w;
    *(float4*)&Bs[bkk][bn4] = bv;
    __syncthreads();
    if (k0 + 16 < 256) {  // prefetch next K-slab into registers
      av = *(const float4*)(Ap + k0 + 16);
      bv = *(const float4*)(Bp + (long long)(k0 + 16) * 128);
    }
#pragma unroll
    for (int kk = 0; kk < 16; ++kk) {
      float4 a = *(const float4*)&As[kk][ty << 2];
      float4 b4 = *(const float4*)&Bs[kk][tx << 2];
      acc[0][0] += a.x * b4.x; acc[0][1] += a.x * b4.y; acc[0][2] += a.x * b4.z; acc[0][3] += a.x * b4.w;
      acc[1][0] += a.y * b4.x; acc[1][1] += a.y * b4.y; acc[1][2] += a.y * b4.z; acc[1][3] += a.y * b4.w;
      acc[2][0] += a.z * b4.x; acc[2][1] += a.z * b4.y; acc[2][2] += a.z * b4.z; acc[2][3] += a.z * b4.w;
      acc[3][0] += a.w * b4.x; acc[3][1] += a.w * b4.y; acc[3][2] += a.w * b4.z; acc[3][3] += a.w * b4.w;
    }
  }

#pragma unroll
  for (int i = 0; i < 4; ++i) {
    const int r = mt * 64 + (ty << 2) + i;
    float* Cp = cfg.C + (long long)r * 256 + cfg.ccol0 + nt * 64 + (tx << 2);
#pragma unroll
    for (int j = 0; j < 4; ++j) {
      float v = acc[i][j];
      Cp[j] = v > 0.f ? v : 0.f;
    }
  }
}

// ---------------------------------------------------------------------------
// Kernel 4: fused tail. Per block of 16 batch rows:
//   (a) compute nml1 rows (mean of 10 out1 rows) straight into LDS,
//   (b) stage out0 rows into LDS,
//   (c) layer-1 GEMM (both halves) with W streamed per k-slab,
//   (d) relu -> l2-normalize -> Dense(1).
// ---------------------------------------------------------------------------
__global__ __launch_bounds__(256) void tail_fused(
    const float* __restrict__ out0, const float* __restrict__ out1,
    const float* __restrict__ ws1, const float* __restrict__ wn1,
    const float* __restrict__ w_out, const float* __restrict__ b_out,
    float* __restrict__ out) {
  __shared__ __align__(16) float As[16][520];  // [row][0:256 out0 | 256:512 nml1]
  __shared__ __align__(16) float Bs[16][260];  // k-slab of [w_self_1 | w_neigh_1]
  __shared__ __align__(16) float Hs[16][260];  // relu'd hidden for reduction

  const int t = threadIdx.x;
  const int r0 = blockIdx.x * 16;
  const int wv = t >> 6, lane = t & 63;

  // (b) stage out0: 16 rows x 64 float4 = 1024 float4; 4 per thread
#pragma unroll
  for (int i = 0; i < 4; ++i) {
    const int f = t + (i << 8);
    const int row = f >> 6, c4 = f & 63;
    *(float4*)&As[row][c4 << 2] =
        *(const float4*)(out0 + (long long)(r0 + row) * 256 + (c4 << 2));
  }
  // (a) nml1 rows: wave wv computes rows wv*4..wv*4+3 (mean_rows_w<10> order)
#pragma unroll
  for (int rr = 0; rr < 4; ++rr) {
    const int row = (wv << 2) + rr;
    const long long base = (long long)(r0 + row) * 10;
    float4 acc = make_float4(0.f, 0.f, 0.f, 0.f);
#pragma unroll
    for (int c = 0; c < 10; c += 5) {
      float4 v[5];
#pragma unroll
      for (int j = 0; j < 5; ++j)
        v[j] = *(const float4*)(out1 + (base + c + j) * 256 + (lane << 2));
#pragma unroll
      for (int j = 0; j < 5; ++j) {
        acc.x += v[j].x; acc.y += v[j].y; acc.z += v[j].z; acc.w += v[j].w;
      }
    }
    acc.x *= 0.1f; acc.y *= 0.1f; acc.z *= 0.1f; acc.w *= 0.1f;
    *(float4*)&As[row][256 + (lane << 2)] = acc;
  }

  // (c) layer-1 GEMM: thread (m = t/16, cb = t%16) -> 16 output cols of row m
  const int m = t >> 4;
  const int cb = t & 15;
  const int aoff = (cb < 8) ? 0 : 256;

  const int skk = t >> 4;
  const int sc = (t & 15) << 4;
  const float* bbase = (sc < 128) ? ws1 + sc : wn1 + (sc - 128);

  float acc[16] = {};

  for (int k0 = 0; k0 < 256; k0 += 16) {
    const float* bsrc = bbase + (k0 + skk) * 128;
    __syncthreads();  // first iter: covers As staging; later: Bs readers done
#pragma unroll
    for (int u = 0; u < 4; ++u)
      *(float4*)&Bs[skk][sc + (u << 2)] = *(const float4*)(bsrc + (u << 2));
    __syncthreads();
#pragma unroll
    for (int q = 0; q < 16; ++q) {
      const float a = As[m][aoff + k0 + q];
#pragma unroll
      for (int j4 = 0; j4 < 4; ++j4) {
        float4 b4 = *(const float4*)&Bs[q][(cb << 4) + (j4 << 2)];
        acc[j4 * 4 + 0] += a * b4.x;
        acc[j4 * 4 + 1] += a * b4.y;
        acc[j4 * 4 + 2] += a * b4.z;
        acc[j4 * 4 + 3] += a * b4.w;
      }
    }
  }

  // (d) relu -> Hs, then l2-norm + dot(w_out)
#pragma unroll
  for (int j4 = 0; j4 < 4; ++j4) {
    float4 h4;
    h4.x = fmaxf(acc[j4 * 4 + 0], 0.f);
    h4.y = fmaxf(acc[j4 * 4 + 1], 0.f);
    h4.z = fmaxf(acc[j4 * 4 + 2], 0.f);
    h4.w = fmaxf(acc[j4 * 4 + 3], 0.f);
    *(float4*)&Hs[m][(cb << 4) + (j4 << 2)] = h4;
  }
  __syncthreads();

  for (int rr = 0; rr < 4; ++rr) {
    const int row = (wv << 2) + rr;
    float4 h4 = *(const float4*)&Hs[row][lane << 2];
    float4 w4 = *(const float4*)&w_out[lane << 2];
    float ss = h4.x * h4.x + h4.y * h4.y + h4.z * h4.z + h4.w * h4.w;
    float dd = h4.x * w4.x + h4.y * w4.y + h4.z * w4.z + h4.w * w4.w;
    for (int off = 32; off; off >>= 1) {
      ss += __shfl_down(ss, off, 64);
      dd += __shfl_down(dd, off, 64);
    }
    if (lane == 0)
      out[r0 + row] = dd / sqrtf(fmaxf(ss, 1e-12f)) + b_out[0];
  }
}

// ---------------------------------------------------------------------------
extern "C" void kernel_launch(void* const* d_in, const int* in_sizes, int n_in,
                              void* d_out, int out_size, void* d_ws, size_t ws_size,
                              hipStream_t stream) {
  (void)in_sizes; (void)n_in; (void)out_size; (void)ws_size;

  const float* features  = (const float*)d_in[0];  // [100000,256]
  const float* w_self_0  = (const float*)d_in[1];  // [256,128]
  const float* w_neigh_0 = (const float*)d_in[2];  // [256,128]
  const float* w_self_1  = (const float*)d_in[3];  // [256,128]
  const float* w_neigh_1 = (const float*)d_in[4];  // [256,128]
  const float* w_out     = (const float*)d_in[5];  // [256,1]
  const float* b_out     = (const float*)d_in[6];  // [1]
  const int*   node_ids  = (const int*)d_in[7];    // [1024]
  const int*   adj       = (const int*)d_in[8];    // [100000,128]
  float* out = (float*)d_out;                      // [1024]

  char* ws = (char*)d_ws;
  size_t off = 0;
  auto alloc = [&](size_t bytes) -> void* {
    void* p = ws + off;
    off = (off + bytes + 255) & ~(size_t)255;
    return p;
  };
  int*   s1   = (int*)alloc(10240 * sizeof(int));
  float* nm1  = (float*)alloc((size_t)10240 * 256 * 4);  // hop-2 neighbor means
  float* nm0  = (float*)alloc((size_t)1024 * 256 * 4);   // hop-1 neighbor means
  float* out1 = (float*)alloc((size_t)10240 * 256 * 4);  // layer-0 hop-1 hidden
  float* out0 = (float*)alloc((size_t)1024 * 256 * 4);   // layer-0 hop-0 hidden

  // 1) hop-1 sampling (precompute s1; L2-warm for kernel 2)
  sample_hop1<<<40, 256, 0, stream>>>(node_ids, adj, s1, 10240);

  // 2) gather means (hop-2 sample inline; nm0 blocks read s1)
  sample_means<<<2816, 256, 0, stream>>>(s1, adj, features, nm1, nm0);

  // 3) layer-0 GEMMs (flat decode, 704 blocks, register prefetch)
  {
    GemmCfg4 cf;
    cf.c[0] = {features, s1,       w_self_0,  out1, 0,   160, 320};
    cf.c[1] = {nm1,      nullptr,  w_neigh_0, out1, 128, 160, 320};
    cf.c[2] = {features, node_ids, w_self_0,  out0, 0,   16,  32};
    cf.c[3] = {nm0,      nullptr,  w_neigh_0, out0, 128, 16,  32};
    gemm_relu_multi<<<704, 256, 0, stream>>>(cf);
  }

  // 4) fused tail: nml1-in-LDS + layer-1 GEMM + l2-norm + Dense(1)
  tail_fused<<<64, 256, 0, stream>>>(out0, out1, w_self_1, w_neigh_1,
                                     w_out, b_out, out);
}

// Round 8
// 251.926 us; speedup vs baseline: 1.0676x; 1.0676x over previous
//
#include <hip/hip_runtime.h>
#include <math.h>

// ---------------------------------------------------------------------------
// JAX Threefry-2x32 (constexpr for key derivation, device for per-elem hash).
// ---------------------------------------------------------------------------
struct K2 { unsigned a, b; };

__host__ __device__ constexpr unsigned rotl32c(unsigned x, int r) {
  return (x << r) | (x >> (32 - r));
}

__host__ __device__ constexpr K2 threefry2x32(unsigned k0, unsigned k1,
                                              unsigned x0, unsigned x1) {
  const unsigned ks2 = k0 ^ k1 ^ 0x1BD11BDAu;
  const unsigned ks[3] = {k0, k1, ks2};
  const int rotA[4] = {13, 15, 26, 6};
  const int rotB[4] = {17, 29, 16, 24};
  x0 += k0; x1 += k1;
  for (int g = 0; g < 5; ++g) {
    const int* rr = (g & 1) ? rotB : rotA;
    for (int i = 0; i < 4; ++i) {
      x0 += x1;
      x1 = rotl32c(x1, rr[i]);
      x1 ^= x0;
    }
    x0 += ks[(g + 1) % 3];
    x1 += ks[(g + 2) % 3] + (unsigned)(g + 1);
  }
  return K2{x0, x1};
}

// key(42)->(0,42); fold_in(key,k)=threefry(key,(0,k)); partitionable split
// keys[i]=threefry(folded,(0,i)); randint(span=128) uses lower-bits key k2.
__host__ __device__ constexpr K2 hop_key(unsigned k) {
  K2 f = threefry2x32(0u, 42u, 0u, k);
  return threefry2x32(f.a, f.b, 0u, 1u);
}

constexpr K2 HK0 = hop_key(0u);
constexpr K2 HK1 = hop_key(1u);

// ---------------------------------------------------------------------------
// Hop-1 sampling: s1[i] = adj[node_ids[i/10]*128 + ((w0^w1)&127)]
// ---------------------------------------------------------------------------
__global__ __launch_bounds__(256) void sample_hop1(
    const int* __restrict__ ids, const int* __restrict__ adj,
    int* __restrict__ out, int n) {
  int i = blockIdx.x * 256 + threadIdx.x;
  if (i >= n) return;
  K2 r = threefry2x32(HK0.a, HK0.b, 0u, (unsigned)i);
  int col = (int)((r.a ^ r.b) & 127u);
  out[i] = adj[(long long)ids[i / 10] * 128 + col];
}

// ---------------------------------------------------------------------------
// Fused hop-2 sample + gather-mean. One wave per output row (10240 rows).
// ---------------------------------------------------------------------------
__global__ __launch_bounds__(256) void sample_mean_hop2(
    const int* __restrict__ s1, const int* __restrict__ adj,
    const float* __restrict__ feat, float* __restrict__ dst) {
  const int m = blockIdx.x * 4 + (threadIdx.x >> 6);
  const int lane = threadIdx.x & 63;

  const int nid = s1[m];  // wave-uniform
  int srow;
  {
    unsigned i = (unsigned)(m * 25 + (lane < 25 ? lane : 0));
    K2 r = threefry2x32(HK1.a, HK1.b, 0u, i);
    int col = (int)((r.a ^ r.b) & 127u);
    srow = adj[(long long)nid * 128 + col];
  }

  float4 acc = make_float4(0.f, 0.f, 0.f, 0.f);
#pragma unroll
  for (int c = 0; c < 25; c += 5) {
    float4 v[5];
#pragma unroll
    for (int j = 0; j < 5; ++j) {
      long long row = (long long)__shfl(srow, c + j, 64);
      v[j] = *(const float4*)(feat + row * 256 + (lane << 2));
    }
#pragma unroll
    for (int j = 0; j < 5; ++j) {
      acc.x += v[j].x; acc.y += v[j].y; acc.z += v[j].z; acc.w += v[j].w;
    }
  }
  const float invS = 1.f / 25.f;
  acc.x *= invS; acc.y *= invS; acc.z *= invS; acc.w *= invS;
  *(float4*)(dst + (long long)m * 256 + (lane << 2)) = acc;
}

// ---------------------------------------------------------------------------
// Wave-per-row mean of S rows (gathered via idx, or contiguous groups).
// ---------------------------------------------------------------------------
template <int S>
__global__ __launch_bounds__(256) void mean_rows_w(
    const float* __restrict__ src, const int* __restrict__ idx,
    float* __restrict__ dst, float invS) {
  const int m = blockIdx.x * 4 + (threadIdx.x >> 6);
  const int lane = threadIdx.x & 63;
  const long long base = (long long)m * S;

  int srow = 0;
  if (idx) srow = idx[base + (lane < S ? lane : 0)];

  float4 acc = make_float4(0.f, 0.f, 0.f, 0.f);
#pragma unroll
  for (int c = 0; c < S; c += 5) {
    float4 v[5];
#pragma unroll
    for (int j = 0; j < 5; ++j) {
      if (c + j < S) {
        long long row = idx ? (long long)__shfl(srow, c + j, 64) : (base + c + j);
        v[j] = *(const float4*)(src + row * 256 + (lane << 2));
      }
    }
#pragma unroll
    for (int j = 0; j < 5; ++j) {
      if (c + j < S) {
        acc.x += v[j].x; acc.y += v[j].y; acc.z += v[j].z; acc.w += v[j].w;
      }
    }
  }
  acc.x *= invS; acc.y *= invS; acc.z *= invS; acc.w *= invS;
  *(float4*)(dst + (long long)m * 256 + (lane << 2)) = acc;
}

// ---------------------------------------------------------------------------
// Multi-config gather-A GEMM + ReLU. Config selected by blockIdx.z.
// C[m, ccol0 + bcol + n] = relu(A[row(m)] @ B[:, bcol+n]); A [*,256], B [256,128].
// 64x64 tile, 256 threads, 4x4 micro-tile, BK=16, float4 LDS fragments.
// ---------------------------------------------------------------------------
struct GemmCfg {
  const float* A; const int* idx; const float* B; float* C;
  int ccol0; int mtiles;
};
struct GemmCfg4 { GemmCfg c[4]; };

__global__ __launch_bounds__(256) void gemm_relu_multi(GemmCfg4 cfgs) {
  const GemmCfg cfg = cfgs.c[blockIdx.z];
  if ((int)blockIdx.x >= cfg.mtiles) return;

  __shared__ __align__(16) float As[16][68];  // transposed A tile, padded
  __shared__ __align__(16) float Bs[16][68];

  const int t = threadIdx.x;
  const int tx = t & 15, ty = t >> 4;
  const int brow = blockIdx.x * 64;
  const int bcol = blockIdx.y * 64;

  const int arow = t >> 2;
  const int ak4 = (t & 3) << 2;
  const int grow = brow + arow;
  const long long asrc = cfg.idx ? (long long)cfg.idx[grow] : (long long)grow;
  const float* Ap = cfg.A + asrc * 256 + ak4;
  const float* Bp = cfg.B + (t >> 4) * 128 + bcol + ((t & 15) << 2);
  const int bkk = t >> 4;
  const int bn4 = (t & 15) << 2;

  float acc[4][4] = {{0.f}};

  for (int k0 = 0; k0 < 256; k0 += 16) {
    float4 av = *(const float4*)(Ap + k0);
    float4 bv = *(const float4*)(Bp + (long long)k0 * 128);
    __syncthreads();
    As[ak4 + 0][arow] = av.x;
    As[ak4 + 1][arow] = av.y;
    As[ak4 + 2][arow] = av.z;
    As[ak4 + 3][arow] = av.w;
    Bs[bkk][bn4 + 0] = bv.x;
    Bs[bkk][bn4 + 1] = bv.y;
    Bs[bkk][bn4 + 2] = bv.z;
    Bs[bkk][bn4 + 3] = bv.w;
    __syncthreads();
#pragma unroll
    for (int kk = 0; kk < 16; ++kk) {
      float4 a = *(const float4*)&As[kk][ty << 2];
      float4 b = *(const float4*)&Bs[kk][tx << 2];
      acc[0][0] += a.x * b.x; acc[0][1] += a.x * b.y; acc[0][2] += a.x * b.z; acc[0][3] += a.x * b.w;
      acc[1][0] += a.y * b.x; acc[1][1] += a.y * b.y; acc[1][2] += a.y * b.z; acc[1][3] += a.y * b.w;
      acc[2][0] += a.z * b.x; acc[2][1] += a.z * b.y; acc[2][2] += a.z * b.z; acc[2][3] += a.z * b.w;
      acc[3][0] += a.w * b.x; acc[3][1] += a.w * b.y; acc[3][2] += a.w * b.z; acc[3][3] += a.w * b.w;
    }
  }

#pragma unroll
  for (int i = 0; i < 4; ++i) {
    const int r = brow + (ty << 2) + i;
    float* Cp = cfg.C + (long long)r * 256 + cfg.ccol0 + bcol + (tx << 2);
#pragma unroll
    for (int j = 0; j < 4; ++j) {
      float v = acc[i][j];
      Cp[j] = v > 0.f ? v : 0.f;
    }
  }
}

// ---------------------------------------------------------------------------
// Final: out[m] = (h[m] . w_out) / sqrt(max(|h[m]|^2, 1e-12)) + b_out
// ---------------------------------------------------------------------------
__global__ __launch_bounds__(256) void final_kernel(
    const float* __restrict__ h, const float* __restrict__ w,
    const float* __restrict__ b, float* __restrict__ out) {
  const int m = blockIdx.x;
  const int t = threadIdx.x;
  float v = h[(long long)m * 256 + t];
  float wv = w[t];
  float ss = v * v;
  float dd = v * wv;
  for (int off = 32; off; off >>= 1) {
    ss += __shfl_down(ss, off, 64);
    dd += __shfl_down(dd, off, 64);
  }
  __shared__ float s1[4], s2[4];
  const int wid = t >> 6, lane = t & 63;
  if (lane == 0) { s1[wid] = ss; s2[wid] = dd; }
  __syncthreads();
  if (t == 0) {
    float S = s1[0] + s1[1] + s1[2] + s1[3];
    float D = s2[0] + s2[1] + s2[2] + s2[3];
    float n = sqrtf(fmaxf(S, 1e-12f));
    out[m] = D / n + b[0];
  }
}

// ---------------------------------------------------------------------------
extern "C" void kernel_launch(void* const* d_in, const int* in_sizes, int n_in,
                              void* d_out, int out_size, void* d_ws, size_t ws_size,
                              hipStream_t stream) {
  (void)in_sizes; (void)n_in; (void)out_size; (void)ws_size;

  const float* features  = (const float*)d_in[0];  // [100000,256]
  const float* w_self_0  = (const float*)d_in[1];  // [256,128]
  const float* w_neigh_0 = (const float*)d_in[2];  // [256,128]
  const float* w_self_1  = (const float*)d_in[3];  // [256,128]
  const float* w_neigh_1 = (const float*)d_in[4];  // [256,128]
  const float* w_out     = (const float*)d_in[5];  // [256,1]
  const float* b_out     = (const float*)d_in[6];  // [1]
  const int*   node_ids  = (const int*)d_in[7];    // [1024]
  const int*   adj       = (const int*)d_in[8];    // [100000,128]
  float* out = (float*)d_out;                      // [1024]

  char* ws = (char*)d_ws;
  size_t off = 0;
  auto alloc = [&](size_t bytes) -> void* {
    void* p = ws + off;
    off = (off + bytes + 255) & ~(size_t)255;
    return p;
  };
  int*   s1   = (int*)alloc(10240 * sizeof(int));
  float* nm1  = (float*)alloc((size_t)10240 * 256 * 4);
  float* nm0  = (float*)alloc((size_t)1024 * 256 * 4);
  float* out1 = (float*)alloc((size_t)10240 * 256 * 4);
  float* out0 = (float*)alloc((size_t)1024 * 256 * 4);
  float* nml1 = (float*)alloc((size_t)1024 * 256 * 4);
  float* hbuf = (float*)alloc((size_t)1024 * 256 * 4);

  // 1) hop-1 sampling (bit-exact JAX threefry)
  sample_hop1<<<40, 256, 0, stream>>>(node_ids, adj, s1, 10240);

  // 2) fused hop-2 sample + gather-mean; hop-1 gather-mean
  sample_mean_hop2<<<2560, 256, 0, stream>>>(s1, adj, features, nm1);
  mean_rows_w<10><<<256, 256, 0, stream>>>(features, s1, nm0, 0.1f);

  // 3) layer 0: four GEMMs in one dispatch (z-routed)
  {
    GemmCfg4 cf;
    cf.c[0] = {features, s1,       w_self_0,  out1, 0,   160};
    cf.c[1] = {nm1,      nullptr,  w_neigh_0, out1, 128, 160};
    cf.c[2] = {features, node_ids, w_self_0,  out0, 0,   16};
    cf.c[3] = {nm0,      nullptr,  w_neigh_0, out0, 128, 16};
    gemm_relu_multi<<<dim3(160, 2, 4), 256, 0, stream>>>(cf);
  }

  // 4) layer 1
  mean_rows_w<10><<<256, 256, 0, stream>>>(out1, nullptr, nml1, 0.1f);
  {
    GemmCfg4 cf;
    cf.c[0] = {out0, nullptr, w_self_1,  hbuf, 0,   16};
    cf.c[1] = {nml1, nullptr, w_neigh_1, hbuf, 128, 16};
    cf.c[2] = {nullptr, nullptr, nullptr, nullptr, 0, 0};
    cf.c[3] = {nullptr, nullptr, nullptr, nullptr, 0, 0};
    gemm_relu_multi<<<dim3(16, 2, 2), 256, 0, stream>>>(cf);
  }

  // 5) l2-normalize + Dense(1)
  final_kernel<<<1024, 256, 0, stream>>>(hbuf, w_out, b_out, out);
}

// Round 9
// 242.663 us; speedup vs baseline: 1.1083x; 1.0382x over previous
//
#include <hip/hip_runtime.h>
#include <hip/hip_bf16.h>
#include <math.h>

// ---------------------------------------------------------------------------
// JAX Threefry-2x32 (constexpr for key derivation, device for per-elem hash).
// ---------------------------------------------------------------------------
struct K2 { unsigned a, b; };

__host__ __device__ constexpr unsigned rotl32c(unsigned x, int r) {
  return (x << r) | (x >> (32 - r));
}

__host__ __device__ constexpr K2 threefry2x32(unsigned k0, unsigned k1,
                                              unsigned x0, unsigned x1) {
  const unsigned ks2 = k0 ^ k1 ^ 0x1BD11BDAu;
  const unsigned ks[3] = {k0, k1, ks2};
  const int rotA[4] = {13, 15, 26, 6};
  const int rotB[4] = {17, 29, 16, 24};
  x0 += k0; x1 += k1;
  for (int g = 0; g < 5; ++g) {
    const int* rr = (g & 1) ? rotB : rotA;
    for (int i = 0; i < 4; ++i) {
      x0 += x1;
      x1 = rotl32c(x1, rr[i]);
      x1 ^= x0;
    }
    x0 += ks[(g + 1) % 3];
    x1 += ks[(g + 2) % 3] + (unsigned)(g + 1);
  }
  return K2{x0, x1};
}

// key(42)->(0,42); fold_in(key,k)=threefry(key,(0,k)); partitionable split
// keys[i]=threefry(folded,(0,i)); randint(span=128) uses lower-bits key k2.
__host__ __device__ constexpr K2 hop_key(unsigned k) {
  K2 f = threefry2x32(0u, 42u, 0u, k);
  return threefry2x32(f.a, f.b, 0u, 1u);
}

constexpr K2 HK0 = hop_key(0u);
constexpr K2 HK1 = hop_key(1u);

// ---------------------------------------------------------------------------
// bf16 helpers (RNE via __float2bfloat16)
// ---------------------------------------------------------------------------
typedef __attribute__((ext_vector_type(8))) short short8v;
typedef __attribute__((ext_vector_type(4))) float f32x4;

__device__ inline short bf16_of(float f) {
  __hip_bfloat16 h = __float2bfloat16(f);
  return __builtin_bit_cast(short, h);
}

__device__ inline short8v cvt8(float4 a, float4 b) {
  short8v r;
  r[0] = bf16_of(a.x); r[1] = bf16_of(a.y); r[2] = bf16_of(a.z); r[3] = bf16_of(a.w);
  r[4] = bf16_of(b.x); r[5] = bf16_of(b.y); r[6] = bf16_of(b.z); r[7] = bf16_of(b.w);
  return r;
}

// ---------------------------------------------------------------------------
// Kernel 1: hop-1 sampling + W0 prep (convert+transpose to bf16).
//   blocks 0..39  : s1[i] = adj[node_ids[i/10]*128 + rand_col(i)]
//   blocks 40..103: Wt{0,1}[n][k] = bf16(w_{self,neigh}_0[k][n])
// ---------------------------------------------------------------------------
__global__ __launch_bounds__(256) void sample_hop1_wprep(
    const int* __restrict__ ids, const int* __restrict__ adj,
    int* __restrict__ out,
    const float* __restrict__ w0, const float* __restrict__ w1,
    short* __restrict__ Wt0, short* __restrict__ Wt1) {
  const int blk = blockIdx.x;
  if (blk < 40) {
    int i = blk * 256 + threadIdx.x;
    if (i < 10240) {
      K2 r = threefry2x32(HK0.a, HK0.b, 0u, (unsigned)i);
      out[i] = adj[(long long)ids[i / 10] * 128 + (int)((r.a ^ r.b) & 127u)];
    }
  } else {
    // 64 blocks * 256 threads * 4 elems = 65536 = 2 * (256*128)
    int e = (blk - 40) * 256 + threadIdx.x;  // 0..16383
    const int half = e >> 13;                // 8192 threads per half
    const int base = (e & 8191) * 4;         // 0..32764
    const float* W = half ? w1 : w0;
    short* Wt = half ? Wt1 : Wt0;
#pragma unroll
    for (int u = 0; u < 4; ++u) {
      int rr = base + u;                     // 0..32767
      int k = rr >> 7, n = rr & 127;
      Wt[n * 256 + k] = bf16_of(W[k * 128 + n]);
    }
  }
}

// ---------------------------------------------------------------------------
// Fused hop-2 sample + gather-mean. One wave per output row (10240 rows).
// ---------------------------------------------------------------------------
__global__ __launch_bounds__(256) void sample_mean_hop2(
    const int* __restrict__ s1, const int* __restrict__ adj,
    const float* __restrict__ feat, float* __restrict__ dst) {
  const int m = blockIdx.x * 4 + (threadIdx.x >> 6);
  const int lane = threadIdx.x & 63;

  const int nid = s1[m];  // wave-uniform
  int srow;
  {
    unsigned i = (unsigned)(m * 25 + (lane < 25 ? lane : 0));
    K2 r = threefry2x32(HK1.a, HK1.b, 0u, i);
    int col = (int)((r.a ^ r.b) & 127u);
    srow = adj[(long long)nid * 128 + col];
  }

  float4 acc = make_float4(0.f, 0.f, 0.f, 0.f);
#pragma unroll
  for (int c = 0; c < 25; c += 5) {
    float4 v[5];
#pragma unroll
    for (int j = 0; j < 5; ++j) {
      long long row = (long long)__shfl(srow, c + j, 64);
      v[j] = *(const float4*)(feat + row * 256 + (lane << 2));
    }
#pragma unroll
    for (int j = 0; j < 5; ++j) {
      acc.x += v[j].x; acc.y += v[j].y; acc.z += v[j].z; acc.w += v[j].w;
    }
  }
  const float invS = 1.f / 25.f;
  acc.x *= invS; acc.y *= invS; acc.z *= invS; acc.w *= invS;
  *(float4*)(dst + (long long)m * 256 + (lane << 2)) = acc;
}

// ---------------------------------------------------------------------------
// Wave-per-row mean of S rows (gathered via idx, or contiguous groups).
// ---------------------------------------------------------------------------
template <int S>
__global__ __launch_bounds__(256) void mean_rows_w(
    const float* __restrict__ src, const int* __restrict__ idx,
    float* __restrict__ dst, float invS) {
  const int m = blockIdx.x * 4 + (threadIdx.x >> 6);
  const int lane = threadIdx.x & 63;
  const long long base = (long long)m * S;

  int srow = 0;
  if (idx) srow = idx[base + (lane < S ? lane : 0)];

  float4 acc = make_float4(0.f, 0.f, 0.f, 0.f);
#pragma unroll
  for (int c = 0; c < S; c += 5) {
    float4 v[5];
#pragma unroll
    for (int j = 0; j < 5; ++j) {
      if (c + j < S) {
        long long row = idx ? (long long)__shfl(srow, c + j, 64) : (base + c + j);
        v[j] = *(const float4*)(src + row * 256 + (lane << 2));
      }
    }
#pragma unroll
    for (int j = 0; j < 5; ++j) {
      if (c + j < S) {
        acc.x += v[j].x; acc.y += v[j].y; acc.z += v[j].z; acc.w += v[j].w;
      }
    }
  }
  acc.x *= invS; acc.y *= invS; acc.z *= invS; acc.w *= invS;
  *(float4*)(dst + (long long)m * 256 + (lane << 2)) = acc;
}

// ---------------------------------------------------------------------------
// Layer-0 GEMM via MFMA bf16, fully register-resident (no LDS, no barriers).
// Each wave computes a 16Mx64N output tile: D = relu(A[rows] @ Wt^T).
// A fp32 gathered + converted in-register; Wt bf16 [n][k] from wprep.
// z=0: A=F via s1 -> out1[:,0:128);  z=1: A=nm1 -> out1[:,128:256)
// z=2: first 128 wts: A=F via node_ids -> out0[:,0:128); next 128: nm0 -> out0[:,128:256)
// mfma_f32_16x16x32_bf16 layouts: A lane: row=l&15, k=(l>>4)*8+j;
// B lane: col=l&15, k=(l>>4)*8+j; D lane: col=l&15, row=(l>>4)*4+reg.
// ---------------------------------------------------------------------------
__global__ __launch_bounds__(256) void gemm_mfma(
    const float* __restrict__ features, const int* __restrict__ s1,
    const float* __restrict__ nm1, const int* __restrict__ node_ids,
    const float* __restrict__ nm0,
    const short* __restrict__ Wt0, const short* __restrict__ Wt1,
    float* __restrict__ out1, float* __restrict__ out0) {
  const int z = blockIdx.z;
  int wt = blockIdx.x * 4 + (threadIdx.x >> 6);
  const int lane = threadIdx.x & 63;

  const float* A; const int* idx; const short* Wt; float* C; int ccol0;
  if (z == 0)      { if (wt >= 1280) return; A = features; idx = s1;       Wt = Wt0; C = out1; ccol0 = 0; }
  else if (z == 1) { if (wt >= 1280) return; A = nm1;      idx = nullptr;  Wt = Wt1; C = out1; ccol0 = 128; }
  else {
    if (wt >= 256) return;
    if (wt < 128)  { A = features; idx = node_ids; Wt = Wt0; C = out0; ccol0 = 0; }
    else           { A = nm0;      idx = nullptr;  Wt = Wt1; C = out0; ccol0 = 128; wt -= 128; }
  }

  const int mtile = wt >> 1;
  const int n0 = (wt & 1) << 6;  // 0 or 64
  const int row16 = lane & 15;
  const int kb = lane >> 4;      // 0..3

  const int grow = mtile * 16 + row16;
  const long long arow = idx ? (long long)idx[grow] : (long long)grow;
  const float* Ap = A + arow * 256 + kb * 8;
  const short* Bp = Wt + (long long)(n0 + row16) * 256 + kb * 8;

  f32x4 acc[4] = {};
  for (int k0 = 0; k0 < 256; k0 += 32) {
    float4 a0 = *(const float4*)(Ap + k0);
    float4 a1 = *(const float4*)(Ap + k0 + 4);
    short8v af = cvt8(a0, a1);
#pragma unroll
    for (int ns = 0; ns < 4; ++ns) {
      short8v bf = *(const short8v*)(Bp + ns * 16 * 256 + k0);
      acc[ns] = __builtin_amdgcn_mfma_f32_16x16x32_bf16(af, bf, acc[ns], 0, 0, 0);
    }
  }

  const int orow0 = mtile * 16 + kb * 4;
#pragma unroll
  for (int ns = 0; ns < 4; ++ns) {
    const int col = ccol0 + n0 + ns * 16 + row16;
#pragma unroll
    for (int r = 0; r < 4; ++r) {
      float v = acc[ns][r];
      C[(long long)(orow0 + r) * 256 + col] = v > 0.f ? v : 0.f;
    }
  }
}

// ---------------------------------------------------------------------------
// Layer-1 fp32 GEMM (small). Config selected by blockIdx.z.
// 64x64 tile, 4x4 micro, BK=16, float4 LDS fragments.
// ---------------------------------------------------------------------------
struct GemmCfg {
  const float* A; const int* idx; const float* B; float* C;
  int ccol0; int mtiles;
};
struct GemmCfg4 { GemmCfg c[4]; };

__global__ __launch_bounds__(256) void gemm_relu_multi(GemmCfg4 cfgs) {
  const GemmCfg cfg = cfgs.c[blockIdx.z];
  if ((int)blockIdx.x >= cfg.mtiles) return;

  __shared__ __align__(16) float As[16][68];
  __shared__ __align__(16) float Bs[16][68];

  const int t = threadIdx.x;
  const int tx = t & 15, ty = t >> 4;
  const int brow = blockIdx.x * 64;
  const int bcol = blockIdx.y * 64;

  const int arow = t >> 2;
  const int ak4 = (t & 3) << 2;
  const int grow = brow + arow;
  const long long asrc = cfg.idx ? (long long)cfg.idx[grow] : (long long)grow;
  const float* Ap = cfg.A + asrc * 256 + ak4;
  const float* Bp = cfg.B + (t >> 4) * 128 + bcol + ((t & 15) << 2);
  const int bkk = t >> 4;
  const int bn4 = (t & 15) << 2;

  float acc[4][4] = {{0.f}};

  for (int k0 = 0; k0 < 256; k0 += 16) {
    float4 av = *(const float4*)(Ap + k0);
    float4 bv = *(const float4*)(Bp + (long long)k0 * 128);
    __syncthreads();
    As[ak4 + 0][arow] = av.x;
    As[ak4 + 1][arow] = av.y;
    As[ak4 + 2][arow] = av.z;
    As[ak4 + 3][arow] = av.w;
    Bs[bkk][bn4 + 0] = bv.x;
    Bs[bkk][bn4 + 1] = bv.y;
    Bs[bkk][bn4 + 2] = bv.z;
    Bs[bkk][bn4 + 3] = bv.w;
    __syncthreads();
#pragma unroll
    for (int kk = 0; kk < 16; ++kk) {
      float4 a = *(const float4*)&As[kk][ty << 2];
      float4 b = *(const float4*)&Bs[kk][tx << 2];
      acc[0][0] += a.x * b.x; acc[0][1] += a.x * b.y; acc[0][2] += a.x * b.z; acc[0][3] += a.x * b.w;
      acc[1][0] += a.y * b.x; acc[1][1] += a.y * b.y; acc[1][2] += a.y * b.z; acc[1][3] += a.y * b.w;
      acc[2][0] += a.z * b.x; acc[2][1] += a.z * b.y; acc[2][2] += a.z * b.z; acc[2][3] += a.z * b.w;
      acc[3][0] += a.w * b.x; acc[3][1] += a.w * b.y; acc[3][2] += a.w * b.z; acc[3][3] += a.w * b.w;
    }
  }

#pragma unroll
  for (int i = 0; i < 4; ++i) {
    const int r = brow + (ty << 2) + i;
    float* Cp = cfg.C + (long long)r * 256 + cfg.ccol0 + bcol + (tx << 2);
#pragma unroll
    for (int j = 0; j < 4; ++j) {
      float v = acc[i][j];
      Cp[j] = v > 0.f ? v : 0.f;
    }
  }
}

// ---------------------------------------------------------------------------
// Final: out[m] = (h[m] . w_out) / sqrt(max(|h[m]|^2, 1e-12)) + b_out
// ---------------------------------------------------------------------------
__global__ __launch_bounds__(256) void final_kernel(
    const float* __restrict__ h, const float* __restrict__ w,
    const float* __restrict__ b, float* __restrict__ out) {
  const int m = blockIdx.x;
  const int t = threadIdx.x;
  float v = h[(long long)m * 256 + t];
  float wv = w[t];
  float ss = v * v;
  float dd = v * wv;
  for (int off = 32; off; off >>= 1) {
    ss += __shfl_down(ss, off, 64);
    dd += __shfl_down(dd, off, 64);
  }
  __shared__ float s1[4], s2[4];
  const int wid = t >> 6, lane = t & 63;
  if (lane == 0) { s1[wid] = ss; s2[wid] = dd; }
  __syncthreads();
  if (t == 0) {
    float S = s1[0] + s1[1] + s1[2] + s1[3];
    float D = s2[0] + s2[1] + s2[2] + s2[3];
    float n = sqrtf(fmaxf(S, 1e-12f));
    out[m] = D / n + b[0];
  }
}

// ---------------------------------------------------------------------------
extern "C" void kernel_launch(void* const* d_in, const int* in_sizes, int n_in,
                              void* d_out, int out_size, void* d_ws, size_t ws_size,
                              hipStream_t stream) {
  (void)in_sizes; (void)n_in; (void)out_size; (void)ws_size;

  const float* features  = (const float*)d_in[0];  // [100000,256]
  const float* w_self_0  = (const float*)d_in[1];  // [256,128]
  const float* w_neigh_0 = (const float*)d_in[2];  // [256,128]
  const float* w_self_1  = (const float*)d_in[3];  // [256,128]
  const float* w_neigh_1 = (const float*)d_in[4];  // [256,128]
  const float* w_out     = (const float*)d_in[5];  // [256,1]
  const float* b_out     = (const float*)d_in[6];  // [1]
  const int*   node_ids  = (const int*)d_in[7];    // [1024]
  const int*   adj       = (const int*)d_in[8];    // [100000,128]
  float* out = (float*)d_out;                      // [1024]

  char* ws = (char*)d_ws;
  size_t off = 0;
  auto alloc = [&](size_t bytes) -> void* {
    void* p = ws + off;
    off = (off + bytes + 255) & ~(size_t)255;
    return p;
  };
  int*   s1   = (int*)alloc(10240 * sizeof(int));
  float* nm1  = (float*)alloc((size_t)10240 * 256 * 4);
  float* nm0  = (float*)alloc((size_t)1024 * 256 * 4);
  float* out1 = (float*)alloc((size_t)10240 * 256 * 4);
  float* out0 = (float*)alloc((size_t)1024 * 256 * 4);
  float* nml1 = (float*)alloc((size_t)1024 * 256 * 4);
  float* hbuf = (float*)alloc((size_t)1024 * 256 * 4);
  short* Wt0  = (short*)alloc((size_t)128 * 256 * 2);  // bf16 [n][k]
  short* Wt1  = (short*)alloc((size_t)128 * 256 * 2);

  // 1) hop-1 sampling + layer-0 weight prep (bf16 transpose)
  sample_hop1_wprep<<<104, 256, 0, stream>>>(node_ids, adj, s1,
                                             w_self_0, w_neigh_0, Wt0, Wt1);

  // 2) fused hop-2 sample + gather-mean; hop-1 gather-mean
  sample_mean_hop2<<<2560, 256, 0, stream>>>(s1, adj, features, nm1);
  mean_rows_w<10><<<256, 256, 0, stream>>>(features, s1, nm0, 0.1f);

  // 3) layer 0: MFMA bf16 GEMM, register-resident (z-routed configs)
  gemm_mfma<<<dim3(320, 1, 3), 256, 0, stream>>>(
      features, s1, nm1, node_ids, nm0, Wt0, Wt1, out1, out0);

  // 4) layer 1 (fp32, small)
  mean_rows_w<10><<<256, 256, 0, stream>>>(out1, nullptr, nml1, 0.1f);
  {
    GemmCfg4 cf;
    cf.c[0] = {out0, nullptr, w_self_1,  hbuf, 0,   16};
    cf.c[1] = {nml1, nullptr, w_neigh_1, hbuf, 128, 16};
    cf.c[2] = {nullptr, nullptr, nullptr, nullptr, 0, 0};
    cf.c[3] = {nullptr, nullptr, nullptr, nullptr, 0, 0};
    gemm_relu_multi<<<dim3(16, 2, 2), 256, 0, stream>>>(cf);
  }

  // 5) l2-normalize + Dense(1)
  final_kernel<<<1024, 256, 0, stream>>>(hbuf, w_out, b_out, out);
}